// Round 4
// baseline (1667.164 us; speedup 1.0000x reference)
//
#include <hip/hip_runtime.h>

#define CCH 48  // channel count, fixed by the problem

// Count out-degree (row occurrences) of each node.
__global__ void deg_count(const int* __restrict__ row, float* __restrict__ deg, int E) {
    int e = blockIdx.x * blockDim.x + threadIdx.x;
    if (e < E) atomicAdd(&deg[row[e]], 1.0f);
}

// dis[n] = rsqrt(deg[n] + 1)   (+1 = self loop; always > 0 so no guard needed)
__global__ void deg_to_dis(float* __restrict__ deg, int N) {
    int n = blockIdx.x * blockDim.x + threadIdx.x;
    if (n < N) {
        deg[n] = rsqrtf(deg[n] + 1.0f);
    }
}

// 8 threads per edge, 6 fp32 channels per thread (48 = 8*6).
// Channel chunk byte offset = lane*24, 8B-aligned -> float2 loads.
__global__ void edge_scatter(const float* __restrict__ label,
                             const int* __restrict__ row,
                             const int* __restrict__ col,
                             const float* __restrict__ dis,
                             float* __restrict__ acc, int E) {
    long long t = (long long)blockIdx.x * blockDim.x + threadIdx.x;
    int e = (int)(t >> 3);
    if (e >= E) return;
    int l = (int)(t & 7) * 6;  // starting channel
    int r = row[e];
    int c = col[e];
    float norm = dis[r] * dis[c];
    const float2* s = reinterpret_cast<const float2*>(label + (long long)r * CCH + l);
    float* d = acc + (long long)c * CCH + l;
#pragma unroll
    for (int k = 0; k < 3; ++k) {
        float2 u = s[k];
        atomicAdd(d + 2 * k,     u.x * norm);
        atomicAdd(d + 2 * k + 1, u.y * norm);
    }
}

// out[n,c] = acc[n,c] + label[n,c] * dis[n]^2   (self-loop term fused here)
__global__ void finalize(const float* __restrict__ acc,
                         const float* __restrict__ label,
                         const float* __restrict__ dis,
                         float* __restrict__ out, int total) {
    int i = blockIdx.x * blockDim.x + threadIdx.x;
    if (i >= total) return;
    int n = i / CCH;
    float ds = dis[n];
    out[i] = acc[i] + label[i] * (ds * ds);
}

extern "C" void kernel_launch(void* const* d_in, const int* in_sizes, int n_in,
                              void* d_out, int out_size, void* d_ws, size_t ws_size,
                              hipStream_t stream) {
    const float* label = (const float*)d_in[0];  // fp32 (N,48)
    const int* ei = (const int*)d_in[1];         // int32, (2,E) flat

    const int NC = in_sizes[0];       // N * 48
    const int N  = NC / CCH;
    const int E  = in_sizes[1] / 2;
    const int* row = ei;
    const int* col = ei + E;

    // ws layout: [acc: N*C f32][dis: N f32]
    float* acc = (float*)d_ws;
    float* dis = acc + NC;

    // Zero acc + deg(dis) — ws poisoned 0xAA before every call.
    hipMemsetAsync(acc, 0, (size_t)(NC + N) * sizeof(float), stream);

    deg_count<<<(E + 255) / 256, 256, 0, stream>>>(row, dis, E);
    deg_to_dis<<<(N + 255) / 256, 256, 0, stream>>>(dis, N);

    long long tot = (long long)E * 8;
    edge_scatter<<<(unsigned)((tot + 255) / 256), 256, 0, stream>>>(label, row, col, dis, acc, E);

    finalize<<<(NC + 255) / 256, 256, 0, stream>>>(acc, label, dis, (float*)d_out, NC);
}

// Round 5
// 623.682 us; speedup vs baseline: 2.6731x; 2.6731x over previous
//
#include <hip/hip_runtime.h>

#define CCH 48      // channels
#define SCAN_T 1024 // scan block size

// Histogram: row-degree (float, for rsqrt) and col-count (int, for CSR).
__global__ void histo(const int* __restrict__ row, const int* __restrict__ col,
                      float* __restrict__ degf, int* __restrict__ cnt, int E) {
    int e = blockIdx.x * blockDim.x + threadIdx.x;
    if (e >= E) return;
    atomicAdd(&degf[row[e]], 1.0f);
    atomicAdd(&cnt[col[e]], 1);
}

// dis[n] = rsqrt(deg[n] + 1)   (+1 = self loop; always > 0)
__global__ void deg_to_dis(float* __restrict__ deg, int N) {
    int n = blockIdx.x * blockDim.x + threadIdx.x;
    if (n < N) deg[n] = rsqrtf(deg[n] + 1.0f);
}

// Single-block exclusive scan of cnt[N] -> ptr[N] (+ptr[N]=E) and cur[N].
__global__ void __launch_bounds__(SCAN_T) scan_cnt(const int* __restrict__ cnt,
                                                   int* __restrict__ ptr,
                                                   int* __restrict__ cur,
                                                   int N, int E) {
    __shared__ int sm[SCAN_T];
    int tid = threadIdx.x;
    int chunk = (N + SCAN_T - 1) / SCAN_T;
    int lo = tid * chunk;
    int hi = min(lo + chunk, N);
    int s = 0;
    for (int i = lo; i < hi; ++i) s += cnt[i];
    sm[tid] = s;
    __syncthreads();
    // Hillis-Steele inclusive scan in LDS
    for (int off = 1; off < SCAN_T; off <<= 1) {
        int v = (tid >= off) ? sm[tid - off] : 0;
        __syncthreads();
        sm[tid] += v;
        __syncthreads();
    }
    int run = sm[tid] - s;  // exclusive prefix of this thread's chunk
    for (int i = lo; i < hi; ++i) {
        ptr[i] = run;
        cur[i] = run;
        run += cnt[i];
    }
    if (tid == 0) ptr[N] = E;
}

// Fill CSR: for each edge, place its source row id into the col-sorted slot.
__global__ void fill_csr(const int* __restrict__ row, const int* __restrict__ col,
                         int* __restrict__ cur, int* __restrict__ src, int E) {
    int e = blockIdx.x * blockDim.x + threadIdx.x;
    if (e >= E) return;
    int pos = atomicAdd(&cur[col[e]], 1);
    src[pos] = row[e];
}

// Gather: 16 threads per node, 3 channels per thread (48 = 16*3).
// out[n,c] = dis[n] * ( sum_{e: col=n} dis[src]*label[src,c] + dis[n]*label[n,c] )
__global__ void gather(const float* __restrict__ label,
                       const int* __restrict__ ptr,
                       const int* __restrict__ src,
                       const float* __restrict__ dis,
                       float* __restrict__ out, int N) {
    int t = blockIdx.x * blockDim.x + threadIdx.x;
    int n = t >> 4;
    if (n >= N) return;
    int c0 = (t & 15) * 3;
    int beg = ptr[n], end = ptr[n + 1];
    float a0 = 0.f, a1 = 0.f, a2 = 0.f;
    for (int i = beg; i < end; ++i) {
        int s = src[i];
        float w = dis[s];
        const float* p = label + (long long)s * CCH + c0;
        a0 += w * p[0];
        a1 += w * p[1];
        a2 += w * p[2];
    }
    float dn = dis[n];
    const float* q = label + (long long)n * CCH + c0;
    float* o = out + (long long)n * CCH + c0;
    o[0] = dn * (a0 + dn * q[0]);
    o[1] = dn * (a1 + dn * q[1]);
    o[2] = dn * (a2 + dn * q[2]);
}

extern "C" void kernel_launch(void* const* d_in, const int* in_sizes, int n_in,
                              void* d_out, int out_size, void* d_ws, size_t ws_size,
                              hipStream_t stream) {
    const float* label = (const float*)d_in[0];  // fp32 (N,48)
    const int* ei = (const int*)d_in[1];         // int32, (2,E) flat

    const int NC = in_sizes[0];  // N * 48
    const int N  = NC / CCH;
    const int E  = in_sizes[1] / 2;
    const int* row = ei;
    const int* col = ei + E;

    // ws layout: [dis: N f32][cnt: N i32][ptr: N+1 i32][cur: N i32][src: E i32]
    float* dis = (float*)d_ws;
    int* cnt   = (int*)(dis + N);
    int* ptr   = cnt + N;
    int* cur   = ptr + (N + 1);
    int* srcA  = cur + N;

    // Zero dis + cnt (contiguous). ws is poisoned 0xAA before every call.
    hipMemsetAsync(d_ws, 0, (size_t)(2 * N) * sizeof(float), stream);

    histo<<<(E + 255) / 256, 256, 0, stream>>>(row, col, dis, cnt, E);
    deg_to_dis<<<(N + 255) / 256, 256, 0, stream>>>(dis, N);
    scan_cnt<<<1, SCAN_T, 0, stream>>>(cnt, ptr, cur, N, E);
    fill_csr<<<(E + 255) / 256, 256, 0, stream>>>(row, col, cur, srcA, E);

    int threads_gather = N * 16;
    gather<<<(threads_gather + 255) / 256, 256, 0, stream>>>(label, ptr, srcA, dis,
                                                             (float*)d_out, N);
}

// Round 6
// 410.342 us; speedup vs baseline: 4.0629x; 1.5199x over previous
//
#include <hip/hip_runtime.h>

#define CCH 48       // channels
#define TILE 1024    // elements per scan block
#define SBT 256      // scan block threads (4 elements/thread)

// Histogram: row-degree (float, for rsqrt) and col-count (int, for CSR).
__global__ void histo(const int* __restrict__ row, const int* __restrict__ col,
                      float* __restrict__ degf, int* __restrict__ cnt, int E) {
    int e = blockIdx.x * blockDim.x + threadIdx.x;
    if (e >= E) return;
    atomicAdd(&degf[row[e]], 1.0f);
    atomicAdd(&cnt[col[e]], 1);
}

// dis[n] = rsqrt(deg[n] + 1)   (+1 = self loop; always > 0)
__global__ void deg_to_dis(float* __restrict__ deg, int N) {
    int n = blockIdx.x * blockDim.x + threadIdx.x;
    if (n < N) deg[n] = rsqrtf(deg[n] + 1.0f);
}

// Pass 1: per-block tile sums. Block b sums cnt[b*TILE .. b*TILE+TILE) -> bsum[b].
__global__ void __launch_bounds__(SBT) scan_partial(const int* __restrict__ cnt,
                                                    int* __restrict__ bsum, int N) {
    __shared__ int sm[SBT];
    int b = blockIdx.x, tid = threadIdx.x;
    int base = b * TILE + tid * 4;
    int s = 0;
#pragma unroll
    for (int k = 0; k < 4; ++k) {
        int i = base + k;
        s += (i < N) ? cnt[i] : 0;
    }
    sm[tid] = s;
    __syncthreads();
    for (int off = SBT / 2; off > 0; off >>= 1) {
        if (tid < off) sm[tid] += sm[tid + off];
        __syncthreads();
    }
    if (tid == 0) bsum[b] = sm[0];
}

// Pass 2: single small block scans bsum[0..B) exclusive -> boff. Also ptr[N]=E.
__global__ void __launch_bounds__(1024) scan_block(const int* __restrict__ bsum,
                                                   int* __restrict__ boff,
                                                   int* __restrict__ ptr,
                                                   int B, int N, int E) {
    __shared__ int sm[1024];
    int tid = threadIdx.x;
    int v = (tid < B) ? bsum[tid] : 0;
    sm[tid] = v;
    __syncthreads();
    for (int off = 1; off < 1024; off <<= 1) {
        int t = (tid >= off) ? sm[tid - off] : 0;
        __syncthreads();
        sm[tid] += t;
        __syncthreads();
    }
    if (tid < B) boff[tid] = sm[tid] - v;  // exclusive
    if (tid == 0) ptr[N] = E;
}

// Pass 3: block-local exclusive scan + block offset -> ptr, cur.
__global__ void __launch_bounds__(SBT) scan_final(const int* __restrict__ cnt,
                                                  const int* __restrict__ boff,
                                                  int* __restrict__ ptr,
                                                  int* __restrict__ cur, int N) {
    __shared__ int sm[SBT];
    int b = blockIdx.x, tid = threadIdx.x;
    int base = b * TILE + tid * 4;
    int v[4];
    int s = 0;
#pragma unroll
    for (int k = 0; k < 4; ++k) {
        int i = base + k;
        v[k] = (i < N) ? cnt[i] : 0;
        s += v[k];
    }
    sm[tid] = s;
    __syncthreads();
    for (int off = 1; off < SBT; off <<= 1) {
        int t = (tid >= off) ? sm[tid - off] : 0;
        __syncthreads();
        sm[tid] += t;
        __syncthreads();
    }
    int run = boff[b] + sm[tid] - s;  // exclusive prefix for this thread's 4 elems
#pragma unroll
    for (int k = 0; k < 4; ++k) {
        int i = base + k;
        if (i < N) { ptr[i] = run; cur[i] = run; }
        run += v[k];
    }
}

// Fill CSR: for each edge, place its source row id into the col-sorted slot.
__global__ void fill_csr(const int* __restrict__ row, const int* __restrict__ col,
                         int* __restrict__ cur, int* __restrict__ src, int E) {
    int e = blockIdx.x * blockDim.x + threadIdx.x;
    if (e >= E) return;
    int pos = atomicAdd(&cur[col[e]], 1);
    src[pos] = row[e];
}

// Gather: 16 threads per node, 3 channels per thread (48 = 16*3).
// out[n,c] = dis[n] * ( sum_{e: col=n} dis[src]*label[src,c] + dis[n]*label[n,c] )
__global__ void gather(const float* __restrict__ label,
                       const int* __restrict__ ptr,
                       const int* __restrict__ src,
                       const float* __restrict__ dis,
                       float* __restrict__ out, int N) {
    int t = blockIdx.x * blockDim.x + threadIdx.x;
    int n = t >> 4;
    if (n >= N) return;
    int c0 = (t & 15) * 3;
    int beg = ptr[n], end = ptr[n + 1];
    float a0 = 0.f, a1 = 0.f, a2 = 0.f;
    for (int i = beg; i < end; ++i) {
        int s = src[i];
        float w = dis[s];
        const float* p = label + (long long)s * CCH + c0;
        a0 += w * p[0];
        a1 += w * p[1];
        a2 += w * p[2];
    }
    float dn = dis[n];
    const float* q = label + (long long)n * CCH + c0;
    float* o = out + (long long)n * CCH + c0;
    o[0] = dn * (a0 + dn * q[0]);
    o[1] = dn * (a1 + dn * q[1]);
    o[2] = dn * (a2 + dn * q[2]);
}

extern "C" void kernel_launch(void* const* d_in, const int* in_sizes, int n_in,
                              void* d_out, int out_size, void* d_ws, size_t ws_size,
                              hipStream_t stream) {
    const float* label = (const float*)d_in[0];  // fp32 (N,48)
    const int* ei = (const int*)d_in[1];         // int32, (2,E) flat

    const int NC = in_sizes[0];  // N * 48
    const int N  = NC / CCH;
    const int E  = in_sizes[1] / 2;
    const int* row = ei;
    const int* col = ei + E;

    const int B = (N + TILE - 1) / TILE;  // scan blocks (98 for N=100K)

    // ws layout: [dis: N f32][cnt: N i32][ptr: N+1 i32][cur: N i32][src: E i32]
    //            [bsum: B i32][boff: B i32]
    float* dis = (float*)d_ws;
    int* cnt   = (int*)(dis + N);
    int* ptr   = cnt + N;
    int* cur   = ptr + (N + 1);
    int* srcA  = cur + N;
    int* bsum  = srcA + E;
    int* boff  = bsum + B;

    // Zero dis + cnt (contiguous). ws is poisoned 0xAA before every call.
    hipMemsetAsync(d_ws, 0, (size_t)(2 * N) * sizeof(float), stream);

    histo<<<(E + 255) / 256, 256, 0, stream>>>(row, col, dis, cnt, E);
    deg_to_dis<<<(N + 255) / 256, 256, 0, stream>>>(dis, N);

    scan_partial<<<B, SBT, 0, stream>>>(cnt, bsum, N);
    scan_block<<<1, 1024, 0, stream>>>(bsum, boff, ptr, B, N, E);
    scan_final<<<B, SBT, 0, stream>>>(cnt, boff, ptr, cur, N);

    fill_csr<<<(E + 255) / 256, 256, 0, stream>>>(row, col, cur, srcA, E);

    int threads_gather = N * 16;
    gather<<<(threads_gather + 255) / 256, 256, 0, stream>>>(label, ptr, srcA, dis,
                                                             (float*)d_out, N);
}

// Round 7
// 380.489 us; speedup vs baseline: 4.3816x; 1.0785x over previous
//
#include <hip/hip_runtime.h>

#define CCH 48       // channels
#define R 16         // histogram replicas
#define TILE 2048    // elements per scan block (8/thread)
#define SBT 256      // scan block threads

// Replicated histogram: degR[r*N+row]++ , cntR[r*N+col]++ with r = blockIdx&15.
__global__ void histo(const int* __restrict__ row, const int* __restrict__ col,
                      int* __restrict__ degR, int* __restrict__ cntR, int N, int E) {
    int e = blockIdx.x * blockDim.x + threadIdx.x;
    if (e >= E) return;
    long long r = blockIdx.x & (R - 1);
    atomicAdd(&degR[r * N + row[e]], 1);
    atomicAdd(&cntR[r * N + col[e]], 1);
}

// dis[n] = rsqrt(sum_r degR[r*N+n] + 1)
__global__ void reduce_dis(const int* __restrict__ degR, float* __restrict__ dis, int N) {
    int n = blockIdx.x * blockDim.x + threadIdx.x;
    if (n >= N) return;
    int s = 0;
#pragma unroll
    for (int r = 0; r < R; ++r) s += degR[(long long)r * N + n];
    dis[n] = rsqrtf((float)s + 1.0f);
}

// Logical scan order: j = n*R + r  ->  physical cntR[r*N + n].
static __device__ __forceinline__ int cnt_at(const int* __restrict__ cntR, int N, int M, int j) {
    if (j >= M) return 0;
    int r = j & (R - 1);
    int n = j >> 4;
    return cntR[(long long)r * N + n];
}

// Pass 1: per-block tile sums over logical order.
__global__ void __launch_bounds__(SBT) scan_partial(const int* __restrict__ cntR,
                                                    int* __restrict__ bsum, int N, int M) {
    __shared__ int sm[SBT];
    int b = blockIdx.x, tid = threadIdx.x;
    int base = b * TILE + tid * 8;
    int s = 0;
#pragma unroll
    for (int k = 0; k < 8; ++k) s += cnt_at(cntR, N, M, base + k);
    sm[tid] = s;
    __syncthreads();
    for (int off = SBT / 2; off > 0; off >>= 1) {
        if (tid < off) sm[tid] += sm[tid + off];
        __syncthreads();
    }
    if (tid == 0) bsum[b] = sm[0];
}

// Pass 2: single block scans B (<=1024) block sums exclusive -> boff; ptrB[N]=E.
__global__ void __launch_bounds__(1024) scan_block(const int* __restrict__ bsum,
                                                   int* __restrict__ boff,
                                                   int* __restrict__ ptrB,
                                                   int B, int N, int E) {
    __shared__ int sm[1024];
    int tid = threadIdx.x;
    int v = (tid < B) ? bsum[tid] : 0;
    sm[tid] = v;
    __syncthreads();
    for (int off = 1; off < 1024; off <<= 1) {
        int t = (tid >= off) ? sm[tid - off] : 0;
        __syncthreads();
        sm[tid] += t;
        __syncthreads();
    }
    if (tid < B) boff[tid] = sm[tid] - v;
    if (tid == 0) ptrB[N] = E;
}

// Pass 3: block scan + offset; write curR (replica-major) and ptrB (bin starts).
__global__ void __launch_bounds__(SBT) scan_final(const int* __restrict__ cntR,
                                                  const int* __restrict__ boff,
                                                  int* __restrict__ ptrB,
                                                  int* __restrict__ curR, int N, int M) {
    __shared__ int sm[SBT];
    int b = blockIdx.x, tid = threadIdx.x;
    int base = b * TILE + tid * 8;
    int v[8];
    int s = 0;
#pragma unroll
    for (int k = 0; k < 8; ++k) { v[k] = cnt_at(cntR, N, M, base + k); s += v[k]; }
    sm[tid] = s;
    __syncthreads();
    for (int off = 1; off < SBT; off <<= 1) {
        int t = (tid >= off) ? sm[tid - off] : 0;
        __syncthreads();
        sm[tid] += t;
        __syncthreads();
    }
    int run = boff[b] + sm[tid] - s;
#pragma unroll
    for (int k = 0; k < 8; ++k) {
        int j = base + k;
        if (j < M) {
            int r = j & (R - 1);
            int n = j >> 4;
            curR[(long long)r * N + n] = run;
            if (r == 0) ptrB[n] = run;
        }
        run += v[k];
    }
}

// Fill CSR: pos from this block's replica counter; store (src, weight) pair.
__global__ void fill_csr(const int* __restrict__ row, const int* __restrict__ col,
                         const float* __restrict__ dis,
                         int* __restrict__ curR, int2* __restrict__ srcw, int N, int E) {
    int e = blockIdx.x * blockDim.x + threadIdx.x;
    if (e >= E) return;
    long long r = blockIdx.x & (R - 1);
    int rw = row[e];
    int pos = atomicAdd(&curR[r * N + col[e]], 1);
    srcw[pos] = make_int2(rw, __float_as_int(dis[rw]));
}

// Gather: 16 threads per node, 3 channels per thread.
// out[n,c] = dis[n] * ( sum_i w_i * label[src_i, c] + dis[n]*label[n,c] )
__global__ void gather(const float* __restrict__ label,
                       const int* __restrict__ ptrB,
                       const int2* __restrict__ srcw,
                       const float* __restrict__ dis,
                       float* __restrict__ out, int N) {
    int t = blockIdx.x * blockDim.x + threadIdx.x;
    int n = t >> 4;
    if (n >= N) return;
    int c0 = (t & 15) * 3;
    int beg = ptrB[n], end = ptrB[n + 1];
    float a0 = 0.f, a1 = 0.f, a2 = 0.f;
    for (int i = beg; i < end; ++i) {
        int2 sw = srcw[i];
        float w = __int_as_float(sw.y);
        const float* p = label + (long long)sw.x * CCH + c0;
        a0 += w * p[0];
        a1 += w * p[1];
        a2 += w * p[2];
    }
    float dn = dis[n];
    const float* q = label + (long long)n * CCH + c0;
    float* o = out + (long long)n * CCH + c0;
    o[0] = dn * (a0 + dn * q[0]);
    o[1] = dn * (a1 + dn * q[1]);
    o[2] = dn * (a2 + dn * q[2]);
}

extern "C" void kernel_launch(void* const* d_in, const int* in_sizes, int n_in,
                              void* d_out, int out_size, void* d_ws, size_t ws_size,
                              hipStream_t stream) {
    const float* label = (const float*)d_in[0];  // fp32 (N,48)
    const int* ei = (const int*)d_in[1];         // int32, (2,E) flat

    const int NC = in_sizes[0];  // N * 48
    const int N  = NC / CCH;
    const int E  = in_sizes[1] / 2;
    const int* row = ei;
    const int* col = ei + E;

    const int M = R * N;                       // logical scan length
    const int B = (M + TILE - 1) / TILE;       // scan blocks (782 for N=100K)

    // ws layout (ints): [degR: RN][cntR: RN]  <- overlaid later by srcw (2E ints)
    //                   [dis: N f32][ptrB: N+1][curR: RN][bsum: B][boff: B]
    int* degR = (int*)d_ws;
    int* cntR = degR + (long long)M;
    int2* srcw = (int2*)d_ws;                  // overlay: alive only after scans
    long long head = (2LL * M > 2LL * E) ? 2LL * M : 2LL * E;
    float* dis = (float*)d_ws + head;
    int* ptrB  = (int*)(dis + N);
    int* curR  = ptrB + (N + 1);
    int* bsum  = curR + (long long)M;
    int* boff  = bsum + B;

    // Zero degR + cntR. ws is poisoned 0xAA before every call.
    hipMemsetAsync(d_ws, 0, (size_t)(2LL * M) * sizeof(int), stream);

    histo<<<(E + 255) / 256, 256, 0, stream>>>(row, col, degR, cntR, N, E);
    reduce_dis<<<(N + 255) / 256, 256, 0, stream>>>(degR, dis, N);

    scan_partial<<<B, SBT, 0, stream>>>(cntR, bsum, N, M);
    scan_block<<<1, 1024, 0, stream>>>(bsum, boff, ptrB, B, N, E);
    scan_final<<<B, SBT, 0, stream>>>(cntR, boff, ptrB, curR, N, M);

    fill_csr<<<(E + 255) / 256, 256, 0, stream>>>(row, col, dis, curR, srcw, N, E);

    int threads_gather = N * 16;
    gather<<<(threads_gather + 255) / 256, 256, 0, stream>>>(label, ptrB, srcw, dis,
                                                             (float*)d_out, N);
}